// Round 4
// baseline (309.003 us; speedup 1.0000x reference)
//
#include <hip/hip_runtime.h>
#include <hip/hip_bf16.h>

#define B_ 4
#define U_ 16
#define L_ 128
#define H_ 768
#define M_ 256
#define HID_ 150

typedef _Float16 half8 __attribute__((ext_vector_type(8)));
typedef _Float16 half2t __attribute__((ext_vector_type(2)));
typedef float floatx4 __attribute__((ext_vector_type(4)));
typedef float floatx16 __attribute__((ext_vector_type(16)));

// ---------------------------------------------------------------------------
// Kernel 0: prepack weights into MFMA-fragment-contiguous f16 arrays.
// W1cs: 48 kc16 x 5 t1 x 64 lanes x 8.  lane l of (kc,t1) holds
//   A[m = t1*32+(l&31)][k = kc*16+(l>>5)*8+j] = W1c[k][n1=m]  (n1>=150 -> 0)
// W2s: 10 kc2 x 5 t2 x 64 x 8, same layout from W2 (k or n >=150 -> 0)
// W1abs (16x16 frags for pool_hihj): 24 kc32 x 20 u x 64 x 8:
//   B[k = kc*32+(l>>4)*8+j][n = u*16+(l&15)], n<150 -> W1a col n,
//   160<=n<310 -> W1b col n-160, else 0.
// bw: float2[160] = (b2[n], W3[n]) zero-padded.
// ---------------------------------------------------------------------------
__global__ __launch_bounds__(256) void prep_kernel(
    const float* __restrict__ W1, const float* __restrict__ W2,
    const float* __restrict__ b2, const float* __restrict__ W3,
    _Float16* __restrict__ W1cs, _Float16* __restrict__ W2s,
    _Float16* __restrict__ W1abs, float2* __restrict__ bw)
{
    int idx = blockIdx.x * 256 + threadIdx.x;
    if (blockIdx.x == 0 && threadIdx.x < 160) {
        int n = threadIdx.x;
        bw[n] = (n < HID_) ? make_float2(b2[n], W3[n]) : make_float2(0.f, 0.f);
    }
    if (idx < 245760) {   // W1cs
        int j = idx & 7, l = (idx >> 3) & 63;
        int t1 = (idx >> 9) % 5, kc = idx / 2560;
        int n = t1 * 32 + (l & 31);
        int k = kc * 16 + ((l >> 5) << 3) + j;
        W1cs[idx] = (n < HID_) ? (_Float16)W1[(size_t)(2 * H_ + k) * HID_ + n]
                               : (_Float16)0.f;
        return;
    }
    idx -= 245760;
    if (idx < 25600) {    // W2s
        int j = idx & 7, l = (idx >> 3) & 63;
        int t2 = (idx >> 9) % 5, kc = idx / 2560;
        int n = t2 * 32 + (l & 31);
        int k = kc * 16 + ((l >> 5) << 3) + j;
        W2s[idx] = (n < HID_ && k < HID_) ? (_Float16)W2[(size_t)k * HID_ + n]
                                          : (_Float16)0.f;
        return;
    }
    idx -= 25600;
    if (idx < 245760) {   // W1abs
        int j = idx & 7, l = (idx >> 3) & 63;
        int u = (idx >> 9) % 20, kc = idx / 10240;
        int n = u * 16 + (l & 15);
        int k = kc * 32 + ((l >> 4) << 3) + j;
        float v = 0.f;
        if (n < HID_) v = W1[(size_t)k * HID_ + n];
        else if (n >= 160 && n < 160 + HID_) v = W1[(size_t)(H_ + k) * HID_ + (n - 160)];
        W1abs[idx] = (_Float16)v;
    }
}

// ---------------------------------------------------------------------------
// Kernel 1: fused pool + hi/hj projection.
// Block = 16 pooled rows. Phase A: masked mean-pool -> LDS f16 + pooledh.
// Phase B: 16x16x32 MFMA vs W1abs -> hiF[row][160] (b1 folded) and
// hjT[160][1024] (transposed, for coalesced epilogue loads in pair_mlp).
// ---------------------------------------------------------------------------
__global__ __launch_bounds__(256) void pool_hihj_kernel(
    const float* __restrict__ hidden, const int* __restrict__ sutt,
    const int* __restrict__ sstart, const int* __restrict__ send,
    const float* __restrict__ b1, const _Float16* __restrict__ W1abs,
    _Float16* __restrict__ pooledh, float* __restrict__ hiF,
    float* __restrict__ hjT)
{
    __shared__ __align__(16) _Float16 spool[16 * 776];   // pad: +8 per row
    const int blk = blockIdx.x;           // rows blk*16 .. +15
    const int tid = threadIdx.x;

    // ---- phase A: pool 16 rows ----
    for (int r = 0; r < 16; ++r) {
        const int bm = blk * 16 + r;
        const int b  = bm >> 8;
        const int u  = sutt[bm];
        const int st = sstart[bm];
        const int en = send[bm];
        const float inv = 1.0f / (float)(en - st);
        const float* src = hidden + ((size_t)(b * U_ + u) * L_) * H_ + tid * 3;
        float s0 = 0.f, s1 = 0.f, s2 = 0.f;
        for (int l = st; l < en; ++l) {
            const float* p = src + (size_t)l * H_;
            s0 += p[0]; s1 += p[1]; s2 += p[2];
        }
        _Float16 v0 = (_Float16)(s0 * inv), v1 = (_Float16)(s1 * inv),
                 v2 = (_Float16)(s2 * inv);
        spool[r * 776 + tid * 3 + 0] = v0;
        spool[r * 776 + tid * 3 + 1] = v1;
        spool[r * 776 + tid * 3 + 2] = v2;
        _Float16* dst = pooledh + (size_t)bm * H_ + tid * 3;
        dst[0] = v0; dst[1] = v1; dst[2] = v2;
    }
    __syncthreads();

    // ---- phase B: [16 rows] @ W1ab (320 cols as 20 tiles; 5 per wave) ----
    const int w = tid >> 6, lane = tid & 63;
    const int g = lane >> 4, l15 = lane & 15;
    floatx4 acc[5];
    #pragma unroll
    for (int u5 = 0; u5 < 5; ++u5) acc[u5] = (floatx4){0.f, 0.f, 0.f, 0.f};
    const _Float16* aB = &spool[l15 * 776 + g * 8];
    for (int kc = 0; kc < 24; ++kc) {
        half8 av = *(const half8*)(aB + kc * 32);
        #pragma unroll
        for (int u5 = 0; u5 < 5; ++u5) {
            const int u = w * 5 + u5;
            half8 bv = *(const half8*)(W1abs + (size_t)((kc * 20 + u) * 64 + lane) * 8);
            acc[u5] = __builtin_amdgcn_mfma_f32_16x16x32_f16(av, bv, acc[u5], 0, 0, 0);
        }
    }
    const int row0 = blk * 16 + g * 4;
    #pragma unroll
    for (int u5 = 0; u5 < 5; ++u5) {
        const int n = (w * 5 + u5) * 16 + l15;
        if (n < HID_) {
            float b1v = b1[n];
            #pragma unroll
            for (int r = 0; r < 4; ++r)
                hiF[(size_t)(row0 + r) * 160 + n] = acc[u5][r] + b1v;
        } else if (n >= 160 && n < 160 + HID_) {
            *(float4*)&hjT[(size_t)(n - 160) * 1024 + row0] =
                make_float4(acc[u5][0], acc[u5][1], acc[u5][2], acc[u5][3]);
        }
    }
}

// ---------------------------------------------------------------------------
// Kernel 2: fused pair MLP, transposed formulation. 1 wave per block, no LDS,
// no barriers. Wave owns 2 pair-tiles: (i0, jt) and (i0+1, jt), 32 pairs each.
// Stage1: h1^T = relu(W1c^T @ prod^T + ...)   D[row=n1][col=pair]
//   A = W1cs frag (coalesced global), B[k][pair] = pi[i][k]*pj[j][k] (gather).
// Stage2: h2^T = W2^T @ h1^T; B2 built from stage1 C via 4 shfl_xor(32)/chunk.
// Stage3: s = relu(h2^T+b2).W3 + b3, partner-sum via shfl_xor(32).
// C/D 32x32: col=lane&31, row=(reg&3)+8*(reg>>2)+4*(lane>>5).
// A 32x32x16: A[m=lane&31][k=(lane>>5)*8+j]; B: B[k=(lane>>5)*8+j][n=lane&31].
// ---------------------------------------------------------------------------
__global__ __launch_bounds__(64, 2) void pair_mlp_kernel(
    const _Float16* __restrict__ pooledh,
    const float* __restrict__ hiF, const float* __restrict__ hjT,
    const _Float16* __restrict__ W1cs, const _Float16* __restrict__ W2s,
    const float2* __restrict__ bw, const float* __restrict__ b3,
    float* __restrict__ logits)
{
    int q = blockIdx.x;
    const int b = q / 576;
    int r = q - b * 576;
    int jt = 0;
    while (r >= 128 - 16 * jt) { r -= 128 - 16 * jt; ++jt; }
    const int p = 16 * jt + r;           // i-pair: i in {2p, 2p+1}
    const int i0 = 2 * p, j0 = jt * 32;
    const int bm = b * M_;
    const int lane = threadIdx.x & 63;
    const int c31 = lane & 31;
    const int hw = lane >> 5;            // half-wave 0/1

    const _Float16* pjp = pooledh + (size_t)(bm + j0 + c31) * H_ + (hw << 3);
    const _Float16* pip0 = pooledh + (size_t)(bm + i0) * H_ + (hw << 3);
    const _Float16* pip1 = pooledh + (size_t)(bm + i0 + 1) * H_ + (hw << 3);

    floatx16 acc1[2][5];
    #pragma unroll
    for (int t = 0; t < 2; ++t)
        #pragma unroll
        for (int t1 = 0; t1 < 5; ++t1)
            #pragma unroll
            for (int e = 0; e < 16; ++e) acc1[t][t1][e] = 0.f;

    // ---- stage 1: K = 768, 24 chunks of 32 (2 MFMA-k16 each) ----
    for (int kc = 0; kc < 24; ++kc) {
        half8 pj0 = *(const half8*)(pjp + kc * 32);
        half8 pj1 = *(const half8*)(pjp + kc * 32 + 16);
        half8 a00 = *(const half8*)(pip0 + kc * 32) * pj0;
        half8 a01 = *(const half8*)(pip0 + kc * 32 + 16) * pj1;
        half8 a10 = *(const half8*)(pip1 + kc * 32) * pj0;
        half8 a11 = *(const half8*)(pip1 + kc * 32 + 16) * pj1;
        #pragma unroll
        for (int h = 0; h < 2; ++h) {
            const _Float16* wbase = W1cs + (size_t)((kc * 2 + h) * 5) * 512 + lane * 8;
            #pragma unroll
            for (int t1 = 0; t1 < 5; ++t1) {
                half8 wf = *(const half8*)(wbase + t1 * 512);
                acc1[0][t1] = __builtin_amdgcn_mfma_f32_32x32x16_f16(
                    wf, h ? a01 : a00, acc1[0][t1], 0, 0, 0);
                acc1[1][t1] = __builtin_amdgcn_mfma_f32_32x32x16_f16(
                    wf, h ? a11 : a10, acc1[1][t1], 0, 0, 0);
            }
        }
    }

    // ---- epilogue 1: h1 = relu(acc + hiF + hjT), pack to half2 regs ----
    // h1p[t][t1*8 + 2*qd + {0,1}] covers n1loc = 8*qd + 4*hw + {0..3}
    int h1p[2][40];
    #pragma unroll
    for (int t1 = 0; t1 < 5; ++t1) {
        #pragma unroll
        for (int qd = 0; qd < 4; ++qd) {
            const int n1 = t1 * 32 + 8 * qd + 4 * hw;
            float hj0 = hjT[(size_t)(n1 + 0) * 1024 + bm + j0 + c31];
            float hj1 = hjT[(size_t)(n1 + 1) * 1024 + bm + j0 + c31];
            float hj2 = hjT[(size_t)(n1 + 2) * 1024 + bm + j0 + c31];
            float hj3 = hjT[(size_t)(n1 + 3) * 1024 + bm + j0 + c31];
            #pragma unroll
            for (int t = 0; t < 2; ++t) {
                float4 hiv = *(const float4*)&hiF[(size_t)(bm + i0 + t) * 160 + n1];
                float v0 = fmaxf(acc1[t][t1][4 * qd + 0] + hiv.x + hj0, 0.f);
                float v1 = fmaxf(acc1[t][t1][4 * qd + 1] + hiv.y + hj1, 0.f);
                float v2 = fmaxf(acc1[t][t1][4 * qd + 2] + hiv.z + hj2, 0.f);
                float v3 = fmaxf(acc1[t][t1][4 * qd + 3] + hiv.w + hj3, 0.f);
                half2t p01 = {(_Float16)v0, (_Float16)v1};
                half2t p23 = {(_Float16)v2, (_Float16)v3};
                h1p[t][t1 * 8 + 2 * qd + 0] = __builtin_bit_cast(int, p01);
                h1p[t][t1 * 8 + 2 * qd + 1] = __builtin_bit_cast(int, p23);
            }
        }
    }

    // ---- stage 2 + 3, per tile sequentially ----
    const float b3v = b3[0];
    #pragma unroll
    for (int t = 0; t < 2; ++t) {
        floatx16 acc2[5];
        #pragma unroll
        for (int t2 = 0; t2 < 5; ++t2)
            #pragma unroll
            for (int e = 0; e < 16; ++e) acc2[t2][e] = 0.f;

        for (int kc2 = 0; kc2 < 10; ++kc2) {
            const int base = (kc2 >> 1) * 8 + (kc2 & 1) * 4;
            int o0 = h1p[t][base + 0], o1 = h1p[t][base + 1];
            int o2 = h1p[t][base + 2], o3 = h1p[t][base + 3];
            int e0 = __shfl_xor(o0, 32), e1 = __shfl_xor(o1, 32);
            int e2 = __shfl_xor(o2, 32), e3 = __shfl_xor(o3, 32);
            int4 bi;
            bi.x = hw ? e2 : o0;
            bi.y = hw ? e3 : o1;
            bi.z = hw ? o2 : e0;
            bi.w = hw ? o3 : e1;
            half8 b2f = __builtin_bit_cast(half8, bi);
            const _Float16* wbase = W2s + (size_t)(kc2 * 5) * 512 + lane * 8;
            #pragma unroll
            for (int t2 = 0; t2 < 5; ++t2) {
                half8 wf = *(const half8*)(wbase + t2 * 512);
                acc2[t2] = __builtin_amdgcn_mfma_f32_32x32x16_f16(
                    wf, b2f, acc2[t2], 0, 0, 0);
            }
        }

        // stage 3
        float sown = 0.f;
        #pragma unroll
        for (int t2 = 0; t2 < 5; ++t2) {
            #pragma unroll
            for (int qd = 0; qd < 4; ++qd) {
                const int n2 = t2 * 32 + 8 * qd + 4 * hw;
                float4 bw01 = *(const float4*)&bw[n2];
                float4 bw23 = *(const float4*)&bw[n2 + 2];
                sown += fmaxf(acc2[t2][4 * qd + 0] + bw01.x, 0.f) * bw01.y;
                sown += fmaxf(acc2[t2][4 * qd + 1] + bw01.z, 0.f) * bw01.w;
                sown += fmaxf(acc2[t2][4 * qd + 2] + bw23.x, 0.f) * bw23.y;
                sown += fmaxf(acc2[t2][4 * qd + 3] + bw23.z, 0.f) * bw23.w;
            }
        }
        float s = sown + __shfl_xor(sown, 32);
        const int i = i0 + t;
        const int j = j0 + c31;
        if (lane < 32 && j < i)
            logits[(size_t)(bm + i) * M_ + j] = s + b3v;
    }
}

// ---------------------------------------------------------------------------
// Kernel 3: per-row softmax over j<=i, clipped label-mass NLL, atomic sum.
// ---------------------------------------------------------------------------
__global__ __launch_bounds__(256) void loss_kernel(
    const float* __restrict__ logits, const float* __restrict__ labels,
    float* __restrict__ out)
{
    const int bm = blockIdx.x;
    const int i  = bm & (M_ - 1);
    const int j  = threadIdx.x;
    __shared__ float red[4];
    __shared__ float bcast;

    float val = (j < i) ? logits[(size_t)bm * M_ + j]
                        : ((j == i) ? 0.0f : -1e30f);

    float m = val;
    #pragma unroll
    for (int off = 32; off >= 1; off >>= 1) m = fmaxf(m, __shfl_down(m, off, 64));
    const int wave = j >> 6, lane = j & 63;
    if (lane == 0) red[wave] = m;
    __syncthreads();
    if (j == 0) bcast = fmaxf(fmaxf(red[0], red[1]), fmaxf(red[2], red[3]));
    __syncthreads();
    const float mm = bcast;

    float e = (j <= i) ? expf(val - mm) : 0.0f;
    float s = e;
    #pragma unroll
    for (int off = 32; off >= 1; off >>= 1) s += __shfl_down(s, off, 64);
    __syncthreads();
    if (lane == 0) red[wave] = s;
    __syncthreads();
    if (j == 0) bcast = red[0] + red[1] + red[2] + red[3];
    __syncthreads();
    const float ssum = bcast;

    float prob = (j <= i) ? (e / ssum) : -1000.0f;
    float lab = labels[(size_t)bm * M_ + j];
    float tv = prob * lab;
    tv = fminf(fmaxf(tv, 1e-8f), 1.0f - 1e-8f);
    float rs = tv;
    #pragma unroll
    for (int off = 32; off >= 1; off >>= 1) rs += __shfl_down(rs, off, 64);
    __syncthreads();
    if (lane == 0) red[wave] = rs;
    __syncthreads();
    if (j == 0) atomicAdd(out, -logf(red[0] + red[1] + red[2] + red[3]));
}

// ---------------------------------------------------------------------------
extern "C" void kernel_launch(void* const* d_in, const int* in_sizes, int n_in,
                              void* d_out, int out_size, void* d_ws, size_t ws_size,
                              hipStream_t stream)
{
    const float* hidden = (const float*)d_in[0];
    const int*   sutt   = (const int*)d_in[1];
    const int*   sstart = (const int*)d_in[2];
    const int*   send   = (const int*)d_in[3];
    const float* labels = (const float*)d_in[4];
    const float* W1     = (const float*)d_in[5];
    const float* b1     = (const float*)d_in[6];
    const float* W2     = (const float*)d_in[7];
    const float* b2     = (const float*)d_in[8];
    const float* W3     = (const float*)d_in[9];
    const float* b3     = (const float*)d_in[10];

    float* ws = (float*)d_ws;
    float*    hiF     = ws;                          // [1024][160] = 163840
    float*    hjT     = ws + 163840;                 // [160][1024] = 163840
    float*    logits  = ws + 327680;                 // 262144
    float2*   bw      = (float2*)(ws + 589824);      // 160 float2 = 320 fl
    _Float16* pooledh = (_Float16*)(ws + 590144);    // 786432 f16 = 393216 fl
    _Float16* W1cs    = (_Float16*)(ws + 983360);    // 245760 f16 = 122880 fl
    _Float16* W2s     = (_Float16*)(ws + 1106240);   // 25600 f16 = 12800 fl
    _Float16* W1abs   = (_Float16*)(ws + 1119040);   // 245760 f16 = 122880 fl
    float* out = (float*)d_out;

    hipMemsetAsync(d_out, 0, sizeof(float), stream);

    prep_kernel<<<dim3(2020), 256, 0, stream>>>(W1, W2, b2, W3,
                                                W1cs, W2s, W1abs, bw);
    pool_hihj_kernel<<<dim3(64), 256, 0, stream>>>(hidden, sutt, sstart, send,
                                                   b1, W1abs, pooledh, hiF, hjT);
    pair_mlp_kernel<<<dim3(576 * B_), 64, 0, stream>>>(pooledh, hiF, hjT,
                                                       W1cs, W2s, bw, b3, logits);
    loss_kernel<<<dim3(B_ * M_), 256, 0, stream>>>(logits, labels, out);
}

// Round 5
// 214.259 us; speedup vs baseline: 1.4422x; 1.4422x over previous
//
#include <hip/hip_runtime.h>
#include <hip/hip_bf16.h>

#define B_ 4
#define U_ 16
#define L_ 128
#define H_ 768
#define M_ 256
#define HID_ 150

typedef _Float16 half8 __attribute__((ext_vector_type(8)));
typedef _Float16 half4t __attribute__((ext_vector_type(4)));
typedef float floatx4 __attribute__((ext_vector_type(4)));
typedef float floatx16 __attribute__((ext_vector_type(16)));

// ---------------------------------------------------------------------------
// Kernel 0: prepack weights into MFMA-fragment-contiguous f16 arrays.
// W1cs: 48 kc16 x 5 t1 x 64 lanes x 8.  lane l of (kc,t1) holds
//   A[m = t1*32+(l&31)][k = kc*16+(l>>5)*8+j] = W1c[k][n1=m]  (n1>=150 -> 0)
// W2s: 10 kc2 x 5 t2 x 64 x 8, same layout from W2 (k or n >=150 -> 0)
// W1abs (16x16 frags for pool_hihj): 24 kc32 x 20 u x 64 x 8:
//   B[k = kc*32+(l>>4)*8+j][n = u*16+(l&15)], n<150 -> W1a col n,
//   160<=n<310 -> W1b col n-160, else 0.
// bw: float2[160] = (b2[n], W3[n]) zero-padded.
// ---------------------------------------------------------------------------
__global__ __launch_bounds__(256) void prep_kernel(
    const float* __restrict__ W1, const float* __restrict__ W2,
    const float* __restrict__ b2, const float* __restrict__ W3,
    _Float16* __restrict__ W1cs, _Float16* __restrict__ W2s,
    _Float16* __restrict__ W1abs, float2* __restrict__ bw)
{
    int idx = blockIdx.x * 256 + threadIdx.x;
    if (blockIdx.x == 0 && threadIdx.x < 160) {
        int n = threadIdx.x;
        bw[n] = (n < HID_) ? make_float2(b2[n], W3[n]) : make_float2(0.f, 0.f);
    }
    if (idx < 245760) {   // W1cs
        int j = idx & 7, l = (idx >> 3) & 63;
        int t1 = (idx >> 9) % 5, kc = idx / 2560;
        int n = t1 * 32 + (l & 31);
        int k = kc * 16 + ((l >> 5) << 3) + j;
        W1cs[idx] = (n < HID_) ? (_Float16)W1[(size_t)(2 * H_ + k) * HID_ + n]
                               : (_Float16)0.f;
        return;
    }
    idx -= 245760;
    if (idx < 25600) {    // W2s
        int j = idx & 7, l = (idx >> 3) & 63;
        int t2 = (idx >> 9) % 5, kc = idx / 2560;
        int n = t2 * 32 + (l & 31);
        int k = kc * 16 + ((l >> 5) << 3) + j;
        W2s[idx] = (n < HID_ && k < HID_) ? (_Float16)W2[(size_t)k * HID_ + n]
                                          : (_Float16)0.f;
        return;
    }
    idx -= 25600;
    if (idx < 245760) {   // W1abs
        int j = idx & 7, l = (idx >> 3) & 63;
        int u = (idx >> 9) % 20, kc = idx / 10240;
        int n = u * 16 + (l & 15);
        int k = kc * 32 + ((l >> 4) << 3) + j;
        float v = 0.f;
        if (n < HID_) v = W1[(size_t)k * HID_ + n];
        else if (n >= 160 && n < 160 + HID_) v = W1[(size_t)(H_ + k) * HID_ + (n - 160)];
        W1abs[idx] = (_Float16)v;
    }
}

// ---------------------------------------------------------------------------
// Kernel 1: fused pool + hi/hj projection.
// Phase A (parallel): thread = (row r=tid>>4, colgroup cg=tid&15, 48 cols).
// Phase B: 16x16x32 MFMA vs W1abs -> hiF[row][160] (b1 folded) and
// hjT[160][1024] (transposed, coalesced for pair_mlp epilogue).
// ---------------------------------------------------------------------------
__global__ __launch_bounds__(256) void pool_hihj_kernel(
    const float* __restrict__ hidden, const int* __restrict__ sutt,
    const int* __restrict__ sstart, const int* __restrict__ send,
    const float* __restrict__ b1, const _Float16* __restrict__ W1abs,
    _Float16* __restrict__ pooledh, float* __restrict__ hiF,
    float* __restrict__ hjT)
{
    __shared__ __align__(16) _Float16 spool[16 * 776];   // pad: +8 per row
    const int blk = blockIdx.x;           // rows blk*16 .. +15
    const int tid = threadIdx.x;

    // ---- phase A: pool; 16 threads per row, 48 cols per thread ----
    {
        const int r  = tid >> 4;
        const int cg = tid & 15;
        const int bm = blk * 16 + r;
        const int b  = bm >> 8;
        const int u  = sutt[bm];
        const int st = sstart[bm];
        const int en = send[bm];
        const float inv = 1.0f / (float)(en - st);
        const float* src = hidden + ((size_t)(b * U_ + u) * L_) * H_ + cg * 48;
        float4 s[12];
        #pragma unroll
        for (int q = 0; q < 12; ++q) s[q] = make_float4(0.f, 0.f, 0.f, 0.f);
        for (int l = st; l < en; ++l) {
            const float* p = src + (size_t)l * H_;
            #pragma unroll
            for (int q = 0; q < 12; ++q) {
                float4 v = *(const float4*)(p + q * 4);
                s[q].x += v.x; s[q].y += v.y; s[q].z += v.z; s[q].w += v.w;
            }
        }
        _Float16* sp = &spool[r * 776 + cg * 48];
        _Float16* gp = pooledh + (size_t)bm * H_ + cg * 48;
        #pragma unroll
        for (int q2 = 0; q2 < 6; ++q2) {
            half8 h;
            float4 a = s[q2 * 2], bv = s[q2 * 2 + 1];
            h[0] = (_Float16)(a.x * inv);  h[1] = (_Float16)(a.y * inv);
            h[2] = (_Float16)(a.z * inv);  h[3] = (_Float16)(a.w * inv);
            h[4] = (_Float16)(bv.x * inv); h[5] = (_Float16)(bv.y * inv);
            h[6] = (_Float16)(bv.z * inv); h[7] = (_Float16)(bv.w * inv);
            *(half8*)(sp + q2 * 8) = h;
            *(half8*)(gp + q2 * 8) = h;
        }
    }
    __syncthreads();

    // ---- phase B: [16 rows] @ W1ab (320 cols as 20 tiles; 5 per wave) ----
    const int w = tid >> 6, lane = tid & 63;
    const int g = lane >> 4, l15 = lane & 15;
    floatx4 acc[5];
    #pragma unroll
    for (int u5 = 0; u5 < 5; ++u5) acc[u5] = (floatx4){0.f, 0.f, 0.f, 0.f};
    const _Float16* aB = &spool[l15 * 776 + g * 8];
    for (int kc = 0; kc < 24; ++kc) {
        half8 av = *(const half8*)(aB + kc * 32);
        #pragma unroll
        for (int u5 = 0; u5 < 5; ++u5) {
            const int u = w * 5 + u5;
            half8 bv = *(const half8*)(W1abs + (size_t)((kc * 20 + u) * 64 + lane) * 8);
            acc[u5] = __builtin_amdgcn_mfma_f32_16x16x32_f16(av, bv, acc[u5], 0, 0, 0);
        }
    }
    const int row0 = blk * 16 + g * 4;
    #pragma unroll
    for (int u5 = 0; u5 < 5; ++u5) {
        const int n = (w * 5 + u5) * 16 + l15;
        if (n < HID_) {
            float b1v = b1[n];
            #pragma unroll
            for (int r = 0; r < 4; ++r)
                hiF[(size_t)(row0 + r) * 160 + n] = acc[u5][r] + b1v;
        } else if (n >= 160 && n < 160 + HID_) {
            *(float4*)&hjT[(size_t)(n - 160) * 1024 + row0] =
                make_float4(acc[u5][0], acc[u5][1], acc[u5][2], acc[u5][3]);
        }
    }
}

// ---------------------------------------------------------------------------
// Kernel 2: fused pair MLP, transposed formulation. 1 wave per block.
// Wave owns 2 pair-tiles: (i0, jt) and (i0+1, jt), 32 pairs each.
// Stage1: h1^T = relu(W1c^T @ prod^T + ...)  D[row=n1][col=pair]
// h1 bounced through 21.3 KB LDS (stride 170 f16: gcd(85,32)=1, no conflicts)
// instead of registers -> peak VGPR ~210 < 256 cap (R4's 103 MB spill fix).
// Stage2: h2^T = W2^T @ h1^T; B2-frags via ds_read_b128 from h1L.
// Stage3: s = relu(h2^T+b2).W3 + b3, partner-sum via shfl_xor(32).
// C/D 32x32: col=lane&31, row=(reg&3)+8*(reg>>2)+4*(lane>>5).   [R4-verified]
// A 32x32x16: A[m=lane&31][k=(lane>>5)*8+j]; B: B[k=(lane>>5)*8+j][n=lane&31].
// ---------------------------------------------------------------------------
__global__ __launch_bounds__(64, 2) void pair_mlp_kernel(
    const _Float16* __restrict__ pooledh,
    const float* __restrict__ hiF, const float* __restrict__ hjT,
    const _Float16* __restrict__ W1cs, const _Float16* __restrict__ W2s,
    const float2* __restrict__ bw, const float* __restrict__ b3,
    float* __restrict__ logits)
{
    __shared__ __align__(16) _Float16 h1L[2 * 32 * 170];   // 21760 B

    int q = blockIdx.x;
    const int b = q / 576;
    int r = q - b * 576;
    int jt = 0;
    while (r >= 128 - 16 * jt) { r -= 128 - 16 * jt; ++jt; }
    const int p = 16 * jt + r;           // i-pair: i in {2p, 2p+1}
    const int i0 = 2 * p, j0 = jt * 32;
    const int bm = b * M_;
    const int lane = threadIdx.x & 63;
    const int c31 = lane & 31;
    const int hw = lane >> 5;            // half-wave 0/1

    const _Float16* pjp  = pooledh + (size_t)(bm + j0 + c31) * H_ + (hw << 3);
    const _Float16* pip0 = pooledh + (size_t)(bm + i0) * H_ + (hw << 3);
    const _Float16* pip1 = pooledh + (size_t)(bm + i0 + 1) * H_ + (hw << 3);

    floatx16 acc1[2][5];
    #pragma unroll
    for (int t = 0; t < 2; ++t)
        #pragma unroll
        for (int t1 = 0; t1 < 5; ++t1)
            #pragma unroll
            for (int e = 0; e < 16; ++e) acc1[t][t1][e] = 0.f;

    // ---- stage 1: K = 768, 24 chunks of 32 (2 MFMA-k16 halves each) ----
    for (int kc = 0; kc < 24; ++kc) {
        half8 pj0 = *(const half8*)(pjp + kc * 32);
        half8 pj1 = *(const half8*)(pjp + kc * 32 + 16);
        #pragma unroll
        for (int h = 0; h < 2; ++h) {
            half8 pj = h ? pj1 : pj0;
            half8 a0 = *(const half8*)((h ? pip0 + 16 : pip0) + kc * 32) * pj;
            half8 a1 = *(const half8*)((h ? pip1 + 16 : pip1) + kc * 32) * pj;
            const _Float16* wbase = W1cs + (size_t)((kc * 2 + h) * 5) * 512 + lane * 8;
            #pragma unroll
            for (int t1 = 0; t1 < 5; ++t1) {
                half8 wf = *(const half8*)(wbase + t1 * 512);
                acc1[0][t1] = __builtin_amdgcn_mfma_f32_32x32x16_f16(
                    wf, a0, acc1[0][t1], 0, 0, 0);
                acc1[1][t1] = __builtin_amdgcn_mfma_f32_32x32x16_f16(
                    wf, a1, acc1[1][t1], 0, 0, 0);
            }
        }
    }

    // ---- epilogue 1: h1 = relu(acc + hiF + hjT) -> LDS (f16) ----
    #pragma unroll
    for (int t1 = 0; t1 < 5; ++t1) {
        #pragma unroll
        for (int qd = 0; qd < 4; ++qd) {
            const int n1 = t1 * 32 + 8 * qd + 4 * hw;
            float hj0 = hjT[(size_t)(n1 + 0) * 1024 + bm + j0 + c31];
            float hj1 = hjT[(size_t)(n1 + 1) * 1024 + bm + j0 + c31];
            float hj2 = hjT[(size_t)(n1 + 2) * 1024 + bm + j0 + c31];
            float hj3 = hjT[(size_t)(n1 + 3) * 1024 + bm + j0 + c31];
            #pragma unroll
            for (int t = 0; t < 2; ++t) {
                float4 hiv = *(const float4*)&hiF[(size_t)(bm + i0 + t) * 160 + n1];
                half4t hv;
                hv[0] = (_Float16)fmaxf(acc1[t][t1][4 * qd + 0] + hiv.x + hj0, 0.f);
                hv[1] = (_Float16)fmaxf(acc1[t][t1][4 * qd + 1] + hiv.y + hj1, 0.f);
                hv[2] = (_Float16)fmaxf(acc1[t][t1][4 * qd + 2] + hiv.z + hj2, 0.f);
                hv[3] = (_Float16)fmaxf(acc1[t][t1][4 * qd + 3] + hiv.w + hj3, 0.f);
                *(half4t*)&h1L[(t * 32 + c31) * 170 + n1] = hv;
            }
        }
    }
    __syncthreads();   // single wave: cheap; forces LDS visibility

    // ---- stage 2 + 3, per tile sequentially ----
    const float b3v = b3[0];
    #pragma unroll
    for (int t = 0; t < 2; ++t) {
        floatx16 acc2[5];
        #pragma unroll
        for (int t2 = 0; t2 < 5; ++t2)
            #pragma unroll
            for (int e = 0; e < 16; ++e) acc2[t2][e] = 0.f;

        for (int kc2 = 0; kc2 < 10; ++kc2) {
            half8 b2f = *(const half8*)&h1L[(t * 32 + c31) * 170 + kc2 * 16 + hw * 8];
            const _Float16* wbase = W2s + (size_t)(kc2 * 5) * 512 + lane * 8;
            #pragma unroll
            for (int t2 = 0; t2 < 5; ++t2) {
                half8 wf = *(const half8*)(wbase + t2 * 512);
                acc2[t2] = __builtin_amdgcn_mfma_f32_32x32x16_f16(
                    wf, b2f, acc2[t2], 0, 0, 0);
            }
        }

        // stage 3
        float sown = 0.f;
        #pragma unroll
        for (int t2 = 0; t2 < 5; ++t2) {
            #pragma unroll
            for (int qd = 0; qd < 4; ++qd) {
                const int n2 = t2 * 32 + 8 * qd + 4 * hw;
                float4 bw01 = *(const float4*)&bw[n2];
                float4 bw23 = *(const float4*)&bw[n2 + 2];
                sown += fmaxf(acc2[t2][4 * qd + 0] + bw01.x, 0.f) * bw01.y;
                sown += fmaxf(acc2[t2][4 * qd + 1] + bw01.z, 0.f) * bw01.w;
                sown += fmaxf(acc2[t2][4 * qd + 2] + bw23.x, 0.f) * bw23.y;
                sown += fmaxf(acc2[t2][4 * qd + 3] + bw23.z, 0.f) * bw23.w;
            }
        }
        float s = sown + __shfl_xor(sown, 32);
        const int i = i0 + t;
        const int j = j0 + c31;
        if (lane < 32 && j < i)
            logits[(size_t)(bm + i) * M_ + j] = s + b3v;
    }
}

// ---------------------------------------------------------------------------
// Kernel 3: per-row softmax over j<=i, clipped label-mass NLL, atomic sum.
// ---------------------------------------------------------------------------
__global__ __launch_bounds__(256) void loss_kernel(
    const float* __restrict__ logits, const float* __restrict__ labels,
    float* __restrict__ out)
{
    const int bm = blockIdx.x;
    const int i  = bm & (M_ - 1);
    const int j  = threadIdx.x;
    __shared__ float red[4];
    __shared__ float bcast;

    float val = (j < i) ? logits[(size_t)bm * M_ + j]
                        : ((j == i) ? 0.0f : -1e30f);

    float m = val;
    #pragma unroll
    for (int off = 32; off >= 1; off >>= 1) m = fmaxf(m, __shfl_down(m, off, 64));
    const int wave = j >> 6, lane = j & 63;
    if (lane == 0) red[wave] = m;
    __syncthreads();
    if (j == 0) bcast = fmaxf(fmaxf(red[0], red[1]), fmaxf(red[2], red[3]));
    __syncthreads();
    const float mm = bcast;

    float e = (j <= i) ? expf(val - mm) : 0.0f;
    float s = e;
    #pragma unroll
    for (int off = 32; off >= 1; off >>= 1) s += __shfl_down(s, off, 64);
    __syncthreads();
    if (lane == 0) red[wave] = s;
    __syncthreads();
    if (j == 0) bcast = red[0] + red[1] + red[2] + red[3];
    __syncthreads();
    const float ssum = bcast;

    float prob = (j <= i) ? (e / ssum) : -1000.0f;
    float lab = labels[(size_t)bm * M_ + j];
    float tv = prob * lab;
    tv = fminf(fmaxf(tv, 1e-8f), 1.0f - 1e-8f);
    float rs = tv;
    #pragma unroll
    for (int off = 32; off >= 1; off >>= 1) rs += __shfl_down(rs, off, 64);
    __syncthreads();
    if (lane == 0) red[wave] = rs;
    __syncthreads();
    if (j == 0) atomicAdd(out, -logf(red[0] + red[1] + red[2] + red[3]));
}

// ---------------------------------------------------------------------------
extern "C" void kernel_launch(void* const* d_in, const int* in_sizes, int n_in,
                              void* d_out, int out_size, void* d_ws, size_t ws_size,
                              hipStream_t stream)
{
    const float* hidden = (const float*)d_in[0];
    const int*   sutt   = (const int*)d_in[1];
    const int*   sstart = (const int*)d_in[2];
    const int*   send   = (const int*)d_in[3];
    const float* labels = (const float*)d_in[4];
    const float* W1     = (const float*)d_in[5];
    const float* b1     = (const float*)d_in[6];
    const float* W2     = (const float*)d_in[7];
    const float* b2     = (const float*)d_in[8];
    const float* W3     = (const float*)d_in[9];
    const float* b3     = (const float*)d_in[10];

    float* ws = (float*)d_ws;
    float*    hiF     = ws;                          // [1024][160] = 163840
    float*    hjT     = ws + 163840;                 // [160][1024] = 163840
    float*    logits  = ws + 327680;                 // 262144
    float2*   bw      = (float2*)(ws + 589824);      // 160 float2 = 320 fl
    _Float16* pooledh = (_Float16*)(ws + 590144);    // 786432 f16 = 393216 fl
    _Float16* W1cs    = (_Float16*)(ws + 983360);    // 245760 f16 = 122880 fl
    _Float16* W2s     = (_Float16*)(ws + 1106240);   // 25600 f16 = 12800 fl
    _Float16* W1abs   = (_Float16*)(ws + 1119040);   // 245760 f16 = 122880 fl
    float* out = (float*)d_out;

    hipMemsetAsync(d_out, 0, sizeof(float), stream);

    prep_kernel<<<dim3(2020), 256, 0, stream>>>(W1, W2, b2, W3,
                                                W1cs, W2s, W1abs, bw);
    pool_hihj_kernel<<<dim3(64), 256, 0, stream>>>(hidden, sutt, sstart, send,
                                                   b1, W1abs, pooledh, hiF, hjT);
    pair_mlp_kernel<<<dim3(576 * B_), 64, 0, stream>>>(pooledh, hiF, hjT,
                                                       W1cs, W2s, bw, b3, logits);
    loss_kernel<<<dim3(B_ * M_), 256, 0, stream>>>(logits, labels, out);
}